// Round 4
// baseline (385.989 us; speedup 1.0000x reference)
//
#include <hip/hip_runtime.h>

// CubicBSplineFFD: v (4,3,42,42,42) f32 -> out (4,3,192,192,192) f32.
// Closed form after collapsing the 3 stride-5 transposed convs + crop(5,197):
//   out[m] = sum_{d=0..3} B_d(r/5) * v[a+d],  a = m/5, r = m%5   (per axis)
// Weights: d=0: (1-f)^3/6, d=1: B(f), d=2: B(1-f), d=3: f^3/6, f=r/5.
// All control indices a..a+3 in [0,42) for m in [0,192): no bounds logic.
//
// R4 = R2 resubmitted verbatim (3rd attempt): R2 died to container-infra
// flake, R3 died to GPU-acquisition timeout (broker at capacity). The
// redesign has never actually run; static audit found no hazard, so we
// measure before mutating.
//
// R2 redesign vs 364us (146us kernel + 218us harness re-poison fill):
// previous kernel was phase-convoyed: 8 identical resident blocks hit their
// barrier-separated compute phases in lockstep, so HBM stores had ~40% duty
// cycle (2.3 TB/s effective vs 6.2 TB/s the fill achieves). This version is
// BARRIER-FREE per column: one wave owns one (x,y) column per iteration.
//   lane = control z-index: 16 global loads (L1-hot, 10.7KB/block working
//   set) + 20 FMA = x/y-conv in registers; z-conv redistributes t2 across
//   lanes with 5 ds_bpermute (register-only, no LDS round trip, no barrier);
//   per-lane z-quad weights wz[4][5] hoisted out of the column loop.
// Each iteration ends in one dense 768B wave store -> stores spread over
// ~95% of kernel duration instead of 3 synchronized bursts.

#define CPN 42
#define IMG 192
#define TXX 6       // x tile per block
#define TYY 6       // y tile per block
#define NTHREADS 256
#define SLICE (CPN * CPN * CPN)   // 74088

__device__ __forceinline__ float bsp_w_rt(int r, int d) {
  double f = (double)r / 5.0;
  double g = (double)(5 - r) / 5.0;
  double w;
  if (d == 0)      { w = g * g * g / 6.0; }
  else if (d == 1) { w = 2.0 / 3.0 + (0.5 * f - 1.0) * f * f; }
  else if (d == 2) { w = 2.0 / 3.0 + (0.5 * g - 1.0) * g * g; }
  else             { w = f * f * f / 6.0; }
  return (float)w;
}

__global__ void __launch_bounds__(NTHREADS) ffd_kernel(
    const float* __restrict__ v, float* __restrict__ out) {
  const int tid = threadIdx.x;
  const int w = tid >> 6;        // wave id 0..3
  const int lane = tid & 63;
  const int bx = blockIdx.x;     // x tile (0..31)
  const int by = blockIdx.y;     // y tile (0..31)
  const int sl = blockIdx.z;     // fused (batch,dim) slice (0..11)
  const int x0 = bx * TXX;
  const int y0 = by * TYY;

  __shared__ float wtab[20];     // wtab[r*4+d] = B-spline weight
  if (tid < 20) wtab[tid] = bsp_w_rt(tid >> 2, tid & 3);
  __syncthreads();               // the only barrier in the kernel

  // ---- per-lane z-quad constants (lane q stores out z = 4q..4q+3) ----
  const int q = lane < 48 ? lane : 47;      // lanes 48..63: harmless clamp
  const int c0 = (4 * q) / 5;               // first control idx of the quad
  float wz[4][5];                            // dense 5-tap weights per k
#pragma unroll
  for (int k = 0; k < 4; ++k) {
    int z = 4 * q + k;
    int c = z / 5;
    int r = z - 5 * c;
    int off = c - c0;                        // 0 or 1
#pragma unroll
    for (int t = 0; t < 5; ++t) {
      int d = t - off;
      // in-range taps pick wtab[r*4+d] (runtime LDS index: fine), else 0
      wz[k][t] = (d >= 0 && d < 4) ? wtab[r * 4 + d] : 0.0f;
    }
  }

  const float* vs = v + (size_t)sl * SLICE;
  float* os = out + (size_t)sl * ((size_t)IMG * IMG * IMG);
  const int cc = lane < 42 ? lane : 41;     // clamp load lane (no OOB reads)

  // ---- column loop: wave w handles columns w, w+4, ..., w+32 (9 total) ----
  for (int i = 0; i < 9; ++i) {
    int col = w + 4 * i;
    int xi = col / 6;
    int yi = col - 6 * xi;
    int x = x0 + xi;
    int y = y0 + yi;
    int ax = x / 5, rx = x - 5 * ax;
    int ay = y / 5, ry = y - 5 * ay;
    // wave-uniform weights (LDS broadcast reads)
    float wx0 = wtab[rx * 4 + 0], wx1 = wtab[rx * 4 + 1];
    float wx2 = wtab[rx * 4 + 2], wx3 = wtab[rx * 4 + 3];
    float wy0 = wtab[ry * 4 + 0], wy1 = wtab[ry * 4 + 1];
    float wy2 = wtab[ry * 4 + 2], wy3 = wtab[ry * 4 + 3];

    // ---- 2D conv in registers: t2[c] on lane c (16 L1-hot loads) ----
    const float* vb = vs + (ax * CPN + ay) * CPN + cc;
    float t2 = 0.0f;
#pragma unroll
    for (int dx = 0; dx < 4; ++dx) {
      const float* vp = vb + dx * (CPN * CPN);
      float s = wy0 * vp[0];
      s = fmaf(wy1, vp[CPN], s);
      s = fmaf(wy2, vp[2 * CPN], s);
      s = fmaf(wy3, vp[3 * CPN], s);
      float wx = (dx == 0) ? wx0 : (dx == 1) ? wx1 : (dx == 2) ? wx2 : wx3;
      t2 = fmaf(wx, s, t2);
    }

    // ---- z conv: pull t2 from lanes c0..c0+4 (register-only bpermute) ----
    int t2i = __float_as_int(t2);
    float s[5];
#pragma unroll
    for (int t = 0; t < 5; ++t)
      s[t] = __int_as_float(
          __builtin_amdgcn_ds_bpermute((c0 + t) << 2, t2i));

    float res[4];
#pragma unroll
    for (int k = 0; k < 4; ++k) {
      float a = wz[k][0] * s[0];
      a = fmaf(wz[k][1], s[1], a);
      a = fmaf(wz[k][2], s[2], a);
      a = fmaf(wz[k][3], s[3], a);
      a = fmaf(wz[k][4], s[4], a);
      res[k] = a;
    }

    // ---- store: lanes 0..47 write one float4 each = 768B dense/column ----
    if (lane < 48) {
      float4 val = make_float4(res[0], res[1], res[2], res[3]);
      *reinterpret_cast<float4*>(
          os + (size_t)(x * IMG + y) * IMG + 4 * lane) = val;
    }
  }
}

extern "C" void kernel_launch(void* const* d_in, const int* in_sizes, int n_in,
                              void* d_out, int out_size, void* d_ws, size_t ws_size,
                              hipStream_t stream) {
  (void)in_sizes; (void)n_in; (void)d_ws; (void)ws_size; (void)out_size;
  const float* v = (const float*)d_in[0];
  float* out = (float*)d_out;
  dim3 grid(IMG / TXX, IMG / TYY, 12);   // 32 x 32 x 12
  ffd_kernel<<<grid, NTHREADS, 0, stream>>>(v, out);
}